// Round 7
// baseline (546.856 us; speedup 1.0000x reference)
//
#include <hip/hip_runtime.h>

// GlobalInteraction r7 — FULLY FUSED.
// B=4096, N_GLOBAL=64, D=256, E=4, TPE=16, F=4096.
// X:(B,64,256) f32; W1:(E,4096,256); b1:(E,256); W2:(E,256,4096); b2:(E,4096);
// gamma,beta:(E,256). Out:(B,64,256) f32.
//
// pack_w1/pack_w2: weights -> MFMA B-fragment order (64 lanes x 8 bf16 = 1KB
// per 16n x 32k fragment) so every B load is one coalesced 1KB burst.
// fused_kernel: block = (m-tile of 16 b's, expert e). LDS holds Xf (swizzled
// bf16 activations, later overwritten in-place by Y0), H, and P. No
// intermediate HBM traffic. e = blockIdx&3 pins one expert's 4MB packed
// weights per XCD L2.

typedef __attribute__((ext_vector_type(4))) float f32x4;
typedef __bf16 bf16;
typedef __attribute__((ext_vector_type(8))) bf16 bf16x8;

#define DEV static __device__ __forceinline__

DEV f32x4 zero4() { return f32x4{0.f, 0.f, 0.f, 0.f}; }

DEV bf16x8 cvt8(const f32x4& a, const f32x4& b) {
  bf16x8 o;
  o[0] = (bf16)a.x; o[1] = (bf16)a.y; o[2] = (bf16)a.z; o[3] = (bf16)a.w;
  o[4] = (bf16)b.x; o[5] = (bf16)b.y; o[6] = (bf16)b.z; o[7] = (bf16)b.w;
  return o;
}

// ---------------------------------------------------------------------------
// pack_w1: W1 (E,4096,256) f32 -> fragment-packed bf16.
// Frag (kc,nf): lane l, elem j = W1[e][kc*32+(l>>4)*8+j][nf*16+(l&15)]
// ---------------------------------------------------------------------------
__global__ __launch_bounds__(256) void pack_w1(const float* __restrict__ W1,
                                               bf16* __restrict__ P) {
  const int e = blockIdx.z, kc = blockIdx.y;
  const int nf = blockIdx.x * 4 + (threadIdx.x >> 6);
  const int l = threadIdx.x & 63;
  const float* src = W1 + (size_t)e * 4096 * 256 +
                     (size_t)(kc * 32 + (l >> 4) * 8) * 256 + nf * 16 + (l & 15);
  bf16x8 o;
#pragma unroll
  for (int j = 0; j < 8; j++) o[j] = (bf16)src[(size_t)j * 256];
  *(bf16x8*)&P[(((size_t)e * 128 + kc) * 16 + nf) * 512 + l * 8] = o;
}

// ---------------------------------------------------------------------------
// pack_w2: W2 (E,256,4096) f32 -> fragment-packed bf16.
// Frag (t,nfl,kc): lane l, j = W2[e][kc*32+(l>>4)*8+j][t*256+nfl*16+(l&15)]
// ---------------------------------------------------------------------------
__global__ __launch_bounds__(256) void pack_w2(const float* __restrict__ W2,
                                               bf16* __restrict__ P) {
  const int e = blockIdx.z, t = blockIdx.y, kc = blockIdx.x;
  const int l = threadIdx.x & 63;
#pragma unroll
  for (int it = 0; it < 4; it++) {
    int nfl = it * 4 + (threadIdx.x >> 6);
    const float* src = W2 + (size_t)e * 256 * 4096 +
                       (size_t)(kc * 32 + (l >> 4) * 8) * 4096 + t * 256 +
                       nfl * 16 + (l & 15);
    bf16x8 o;
#pragma unroll
    for (int j = 0; j < 8; j++) o[j] = (bf16)src[(size_t)j * 4096];
    *(bf16x8*)&P[(((size_t)e * 256 + t * 16 + nfl) * 8 + kc) * 512 + l * 8] = o;
  }
}

// ---------------------------------------------------------------------------
// fused kernel: stage Xf -> gemm1 -> attn (Y0 in-place) -> gemm2+LN -> Out
// ---------------------------------------------------------------------------
__global__ __launch_bounds__(256) void fused_kernel(
    const float* __restrict__ X, const bf16* __restrict__ W1P,
    const bf16* __restrict__ W2P, const float* __restrict__ b1,
    const float* __restrict__ b2, const float* __restrict__ gamma,
    const float* __restrict__ beta, float* __restrict__ Out) {
  // Xf: 16 rows x 4104 (4096 + pad). Holds bf16(X) swizzled; rows overwritten
  // by XpT then Y0 during attn. Hs: H tile. Pl: per-wave softmax P staging.
  __shared__ __align__(16) bf16 Xf[16 * 4104];   // 131,328 B
  __shared__ __align__(16) bf16 Hs[16 * 264];    //   8,448 B
  __shared__ __align__(16) bf16 Pl[4][512];      //   4,096 B

  const int tid = threadIdx.x, lane = tid & 63, w = tid >> 6;
  const int lr = lane & 15, g = lane >> 4;
  const int fid = blockIdx.x;
  const int e = fid & 3;        // expert pinned per XCD (blockIdx%8 RR)
  const int mt = fid >> 2;      // 0..255
  const int b0 = mt * 16;

  // zero P pad cols 16..31 (per-wave buffer, written once)
  {
    bf16* pl = Pl[w];
    for (int q = lane; q < 256; q += 64) {
      int row = q >> 4, cc = q & 15;
      pl[row * 32 + 16 + cc] = (bf16)0.f;
    }
  }

  // ---- stage Xf: bf16 cast of X m-tile, XOR-swizzled (unit = bf16x8) ----
  // elem col = col8*8; swizzle sc8 = col8 ^ ((col8>>5)&7)
#pragma unroll
  for (int i = 0; i < 32; i++) {
    int u = i * 256 + tid;
    int row = u >> 9, col8 = u & 511;
    const float* q = X + (size_t)(b0 + row) * 16384 + e * 4096 + col8 * 8;
    f32x4 v0 = *(const f32x4*)q;
    f32x4 v1 = *(const f32x4*)(q + 4);
    int sc8 = col8 ^ ((col8 >> 5) & 7);
    *(bf16x8*)&Xf[row * 4104 + sc8 * 8] = cvt8(v0, v1);
  }
  __syncthreads();

  // ---- gemm1: H = relu(Xf @ W1[e] + b1[e]). M=16, wave w owns 64 cols ----
  {
    const bf16* Wp = W1P + (size_t)e * (128 * 16 * 512) + lane * 8;
    f32x4 acc[4];
#pragma unroll
    for (int j = 0; j < 4; j++) acc[j] = zero4();
#pragma unroll 4
    for (int kc = 0; kc < 128; kc++) {
      int col8 = (kc * 4 + g) ^ ((kc >> 3) & 7);
      bf16x8 a = *(const bf16x8*)&Xf[lr * 4104 + col8 * 8];
      bf16x8 bfr[4];
#pragma unroll
      for (int j = 0; j < 4; j++)
        bfr[j] = *(const bf16x8*)&Wp[(size_t)(kc * 16 + w * 4 + j) * 512];
#pragma unroll
      for (int j = 0; j < 4; j++)
        acc[j] = __builtin_amdgcn_mfma_f32_16x16x32_bf16(a, bfr[j], acc[j], 0, 0, 0);
    }
#pragma unroll
    for (int j = 0; j < 4; j++) {
      int col = w * 64 + j * 16 + lr;
      float bv = b1[e * 256 + col];
#pragma unroll
      for (int r = 0; r < 4; r++)
        Hs[(g * 4 + r) * 264 + col] = (bf16)fmaxf(acc[j][r] + bv, 0.f);
    }
  }
  __syncthreads();  // Xf fully consumed by gemm1; H complete

  // ---- attn: wave w handles pairs p = w*4+q; Y0 overwrites Xf row p ----
  {
    bf16* pl = Pl[w];
    for (int q = 0; q < 4; q++) {
      const int p = w * 4 + q;
      bf16* xr = &Xf[p * 4104];

      // A-frags: lane lr = token, k = c*32+g*8+j (read all before overwrite)
      bf16x8 af[8];
#pragma unroll
      for (int c = 0; c < 8; c++) {
        int col8 = (lr * 32 + c * 4 + g) ^ (lr & 7);
        af[c] = *(const bf16x8*)&xr[col8 * 8];
      }
      asm volatile("s_waitcnt lgkmcnt(0)" ::: "memory");

      // XpT [d][tok] over the same row region (gemm1 done with it)
#pragma unroll
      for (int c = 0; c < 8; c++)
#pragma unroll
        for (int j = 0; j < 8; j++)
          xr[(c * 32 + g * 8 + j) * 16 + lr] = af[c][j];

      // scores = Xp Xp^T (self-MFMA; B-frag == A-frag)
      f32x4 s = zero4();
#pragma unroll
      for (int c = 0; c < 8; c++)
        s = __builtin_amdgcn_mfma_f32_16x16x32_bf16(af[c], af[c], s, 0, 0, 0);

      // softmax rows t=4g+r over m=lr
      float pv[4];
#pragma unroll
      for (int r = 0; r < 4; r++) {
        float v = s[r] * 0.0625f;
        float mx = v;
#pragma unroll
        for (int m = 1; m < 16; m <<= 1) mx = fmaxf(mx, __shfl_xor(mx, m));
        float ev = __expf(v - mx);
        float sum = ev;
#pragma unroll
        for (int m = 1; m < 16; m <<= 1) sum += __shfl_xor(sum, m);
        pv[r] = ev / sum;
      }
#pragma unroll
      for (int r = 0; r < 4; r++) pl[(g * 4 + r) * 32 + lr] = (bf16)pv[r];
      bf16x8 pf = *(const bf16x8*)&pl[lr * 32 + g * 8];

      // PV + residual into regs (lane: tok=g*4+r, d=nc*16+lr)
      float yo[16][4];
#pragma unroll
      for (int nc = 0; nc < 16; nc++) {
        bf16x8 bfr = *(const bf16x8*)&xr[(nc * 16 + lr) * 16 + g * 8];
        f32x4 xd = __builtin_amdgcn_mfma_f32_16x16x32_bf16(pf, bfr, zero4(), 0, 0, 0);
#pragma unroll
        for (int r = 0; r < 4; r++)
          yo[nc][r] = xd[r] + (float)xr[(nc * 16 + lr) * 16 + g * 4 + r];
      }
      asm volatile("s_waitcnt lgkmcnt(0)" ::: "memory");

      // Y0 (= Xdot + Xp) overwrites row p, plain layout [t][d]
#pragma unroll
      for (int nc = 0; nc < 16; nc++)
#pragma unroll
        for (int r = 0; r < 4; r++)
          xr[(g * 4 + r) * 256 + nc * 16 + lr] = (bf16)yo[nc][r];
    }
  }
  __syncthreads();  // all Y0 rows ready

  // ---- gemm2 + LN: wave w owns t = w*4 + tt. A = H (LDS), B = W2P (L2) ----
  {
    bf16x8 ah[8];
#pragma unroll
    for (int kc = 0; kc < 8; kc++)
      ah[kc] = *(const bf16x8*)&Hs[lr * 264 + kc * 32 + g * 8];

    float gv[16], btv[16];
#pragma unroll
    for (int nf = 0; nf < 16; nf++) {
      gv[nf] = gamma[e * 256 + nf * 16 + lr];
      btv[nf] = beta[e * 256 + nf * 16 + lr];
    }
    const bf16* Wp = W2P + (size_t)e * (256 * 8 * 512) + lane * 8;

    for (int tt = 0; tt < 4; tt++) {
      const int t = w * 4 + tt;
      f32x4 acc[16];
#pragma unroll
      for (int nf = 0; nf < 16; nf++) acc[nf] = zero4();

#pragma unroll
      for (int nf = 0; nf < 16; nf++) {
#pragma unroll
        for (int kc = 0; kc < 8; kc++) {
          bf16x8 bfr =
              *(const bf16x8*)&Wp[(size_t)((t * 16 + nf) * 8 + kc) * 512];
          acc[nf] = __builtin_amdgcn_mfma_f32_16x16x32_bf16(ah[kc], bfr,
                                                            acc[nf], 0, 0, 0);
        }
      }

      // bias + residual (Y0 from LDS) + LN stats (rows b = g*4+r)
      float s1[4] = {0.f, 0.f, 0.f, 0.f}, s2[4] = {0.f, 0.f, 0.f, 0.f};
#pragma unroll
      for (int nf = 0; nf < 16; nf++) {
        float bv = b2[e * 4096 + t * 256 + nf * 16 + lr];
#pragma unroll
        for (int r = 0; r < 4; r++) {
          float res = (float)Xf[(g * 4 + r) * 4104 + t * 256 + nf * 16 + lr];
          float v = acc[nf][r] + bv + res;
          acc[nf][r] = v;
          s1[r] += v;
          s2[r] += v * v;
        }
      }
#pragma unroll
      for (int r = 0; r < 4; r++) {
#pragma unroll
        for (int m = 1; m < 16; m <<= 1) {
          s1[r] += __shfl_xor(s1[r], m);
          s2[r] += __shfl_xor(s2[r], m);
        }
      }
      float mu[4], rs[4];
#pragma unroll
      for (int r = 0; r < 4; r++) {
        mu[r] = s1[r] * (1.f / 256.f);
        float var = s2[r] * (1.f / 256.f) - mu[r] * mu[r];
        rs[r] = rsqrtf(var + 1e-5f);
      }
      // store: 16 consecutive lanes (lr) = 64B dense f32 segments
#pragma unroll
      for (int nf = 0; nf < 16; nf++)
#pragma unroll
        for (int r = 0; r < 4; r++)
          Out[(size_t)(b0 + g * 4 + r) * 16384 + e * 4096 + t * 256 +
              nf * 16 + lr] = (acc[nf][r] - mu[r]) * rs[r] * gv[nf] + btv[nf];
    }
  }
}

// ---------------------------------------------------------------------------
extern "C" void kernel_launch(void* const* d_in, const int* in_sizes, int n_in,
                              void* d_out, int out_size, void* d_ws, size_t ws_size,
                              hipStream_t stream) {
  const float* X     = (const float*)d_in[0];
  const float* W1    = (const float*)d_in[1];
  const float* b1    = (const float*)d_in[2];
  const float* W2    = (const float*)d_in[3];
  const float* b2    = (const float*)d_in[4];
  const float* gamma = (const float*)d_in[5];
  const float* beta  = (const float*)d_in[6];
  float* Out = (float*)d_out;

  const size_t MB8 = (size_t)4 * 1048576;  // 4M bf16 elems = 8 MB
  bf16* W1P = (bf16*)d_ws;                 // 8 MB
  bf16* W2P = W1P + MB8;                   // 8 MB

  pack_w1<<<dim3(4, 128, 4), dim3(256), 0, stream>>>(W1, W1P);
  pack_w2<<<dim3(8, 16, 4), dim3(256), 0, stream>>>(W2, W2P);
  fused_kernel<<<dim3(1024), dim3(256), 0, stream>>>(X, W1P, W2P, b1, b2,
                                                     gamma, beta, Out);
}

// Round 8
// 492.266 us; speedup vs baseline: 1.1109x; 1.1109x over previous
//
#include <hip/hip_runtime.h>

// GlobalInteraction: B=4096, N_GLOBAL=64, D=256, E=4, TPE=16, F=TPE*D=4096
// X:(B,64,256) f32; W1:(E,4096,256); b1:(E,256); W2:(E,256,4096); b2:(E,4096);
// gamma,beta:(E,256). Out:(B,64,256) f32.
//
// All GEMM operands fragment-packed (64 lanes x 8 bf16 = 1KB per 16x32 frag).
// gemm2 r8: SWAPPED operands -> mfma(W2frag, Hfrag) puts batch-row in D's
// col=lane&15 and 4 consecutive d's in regs: barrier-free, LDS-free, direct
// f32x4 full-line stores, 2-shuffle LayerNorm. W2 streamed via 3-slot
// register ring (2-deep prefetch), H resident per wave.

typedef __attribute__((ext_vector_type(4))) float f32x4;
typedef __bf16 bf16;
typedef __attribute__((ext_vector_type(8))) bf16 bf16x8;
typedef __attribute__((ext_vector_type(4))) bf16 bf16x4;

#define DEV static __device__ __forceinline__

DEV f32x4 zero4() { return f32x4{0.f, 0.f, 0.f, 0.f}; }

DEV bf16x8 cvt8(const f32x4& a, const f32x4& b) {
  bf16x8 o;
  o[0] = (bf16)a.x; o[1] = (bf16)a.y; o[2] = (bf16)a.z; o[3] = (bf16)a.w;
  o[4] = (bf16)b.x; o[5] = (bf16)b.y; o[6] = (bf16)b.z; o[7] = (bf16)b.w;
  return o;
}

// ---------------------------------------------------------------------------
// pack_w1: W1 (E,4096,256) f32 -> fragment-packed bf16.
// Frag (kc,nf): lane l, elem j = W1[e][kc*32+(l>>4)*8+j][nf*16+(l&15)]
// ---------------------------------------------------------------------------
__global__ __launch_bounds__(256) void pack_w1(const float* __restrict__ W1,
                                               bf16* __restrict__ P) {
  const int e = blockIdx.z, kc = blockIdx.y;
  const int nf = blockIdx.x * 4 + (threadIdx.x >> 6);
  const int l = threadIdx.x & 63;
  const float* src = W1 + (size_t)e * 4096 * 256 +
                     (size_t)(kc * 32 + (l >> 4) * 8) * 256 + nf * 16 + (l & 15);
  bf16x8 o;
#pragma unroll
  for (int j = 0; j < 8; j++) o[j] = (bf16)src[(size_t)j * 256];
  *(bf16x8*)&P[(((size_t)e * 128 + kc) * 16 + nf) * 512 + l * 8] = o;
}

// ---------------------------------------------------------------------------
// pack_w2: W2 (E,256,4096) f32 -> fragment-packed bf16.
// Frag (t,nfl,kc): lane l, j = W2[e][kc*32+(l>>4)*8+j][t*256+nfl*16+(l&15)]
// ---------------------------------------------------------------------------
__global__ __launch_bounds__(256) void pack_w2(const float* __restrict__ W2,
                                               bf16* __restrict__ P) {
  const int e = blockIdx.z, t = blockIdx.y, kc = blockIdx.x;
  const int l = threadIdx.x & 63;
#pragma unroll
  for (int it = 0; it < 4; it++) {
    int nfl = it * 4 + (threadIdx.x >> 6);
    const float* src = W2 + (size_t)e * 256 * 4096 +
                       (size_t)(kc * 32 + (l >> 4) * 8) * 4096 + t * 256 +
                       nfl * 16 + (l & 15);
    bf16x8 o;
#pragma unroll
    for (int j = 0; j < 8; j++) o[j] = (bf16)src[(size_t)j * 4096];
    *(bf16x8*)&P[(((size_t)e * 256 + t * 16 + nfl) * 8 + kc) * 512 + l * 8] = o;
  }
}

// ---------------------------------------------------------------------------
// attn: per (b,e): Y0 = softmax(Xp Xp^T / 16) Xp + Xp. One wave per pair.
// Also emits Xbf (bf16 cast of X) when useXb, for gemm1's A-staging.
// ---------------------------------------------------------------------------
__global__ __launch_bounds__(256) void attn_kernel(const float* __restrict__ X,
                                                   float* __restrict__ Y0f,
                                                   bf16* __restrict__ Y0b,
                                                   bf16* __restrict__ Xbf,
                                                   int useBf, int useXb) {
  __shared__ __align__(16) bf16 XpT[4][4224];
  __shared__ __align__(16) bf16 Pl[4][512];
  const int tid = threadIdx.x, lane = tid & 63, w = tid >> 6;
  const int lr = lane & 15, g = lane >> 4;
  bf16* xt = XpT[w];
  bf16* pl = Pl[w];

  for (int q = lane; q < 256; q += 64) {
    int row = q >> 4, cc = q & 15;
    pl[row * 32 + 16 + cc] = (bf16)0.f;
  }
  xt[4096 + lane] = (bf16)0.f;

  const int p = blockIdx.x * 4 + w;
  const int b = p >> 2, e = p & 3;
  const size_t obase0 = (size_t)b * 16384 + e * 4096;
  const float* Xb = X + obase0;

  bf16x8 af[8];
#pragma unroll
  for (int c = 0; c < 8; c++) {
    const float* q = Xb + lr * 256 + c * 32 + g * 8;
    f32x4 v0 = *(const f32x4*)q;
    f32x4 v1 = *(const f32x4*)(q + 4);
    bf16x8 o = cvt8(v0, v1);
    af[c] = o;
#pragma unroll
    for (int j = 0; j < 8; j++)
      xt[(c * 32 + g * 8 + j) * 16 + lr] = o[j];
    if (useXb) *(bf16x8*)&Xbf[obase0 + lr * 256 + c * 32 + g * 8] = o;
  }

  f32x4 s = zero4();
#pragma unroll
  for (int c = 0; c < 8; c++)
    s = __builtin_amdgcn_mfma_f32_16x16x32_bf16(af[c], af[c], s, 0, 0, 0);

  float pv[4];
#pragma unroll
  for (int r = 0; r < 4; r++) {
    float v = s[r] * 0.0625f;
    float mx = v;
#pragma unroll
    for (int m = 1; m < 16; m <<= 1) mx = fmaxf(mx, __shfl_xor(mx, m));
    float ev = __expf(v - mx);
    float sum = ev;
#pragma unroll
    for (int m = 1; m < 16; m <<= 1) sum += __shfl_xor(sum, m);
    pv[r] = ev / sum;
  }
#pragma unroll
  for (int r = 0; r < 4; r++) pl[(g * 4 + r) * 32 + lr] = (bf16)pv[r];

  bf16x8 pf = *(const bf16x8*)&pl[lr * 32 + g * 8];

  float yo[16][4];
#pragma unroll
  for (int nc = 0; nc < 16; nc++) {
    bf16x8 bfr = *(const bf16x8*)&xt[(nc * 16 + lr) * 16 + g * 8];
    f32x4 xd = __builtin_amdgcn_mfma_f32_16x16x32_bf16(pf, bfr, zero4(), 0, 0, 0);
#pragma unroll
    for (int r = 0; r < 4; r++)
      yo[nc][r] = xd[r] + (float)xt[(nc * 16 + lr) * 16 + g * 4 + r];
  }

#pragma unroll
  for (int nc = 0; nc < 16; nc++)
#pragma unroll
    for (int r = 0; r < 4; r++)
      xt[(g * 4 + r) * 264 + nc * 16 + lr] = (bf16)yo[nc][r];

  const int tok = lane >> 2, cc = lane & 3;
  if (useBf) {
#pragma unroll
    for (int i = 0; i < 8; i++) {
      int d0 = i * 32 + cc * 8;
      bf16x8 v = *(const bf16x8*)&xt[tok * 264 + d0];
      *(bf16x8*)&Y0b[obase0 + tok * 256 + d0] = v;
    }
  } else {
#pragma unroll
    for (int i = 0; i < 8; i++) {
      int d0 = i * 32 + cc * 8;
      bf16x8 v = *(const bf16x8*)&xt[tok * 264 + d0];
      f32x4 a, bb;
      a.x = (float)v[0]; a.y = (float)v[1]; a.z = (float)v[2]; a.w = (float)v[3];
      bb.x = (float)v[4]; bb.y = (float)v[5]; bb.z = (float)v[6]; bb.w = (float)v[7];
      *(f32x4*)&Y0f[obase0 + tok * 256 + d0] = a;
      *(f32x4*)&Y0f[obase0 + tok * 256 + d0 + 4] = bb;
    }
  }
}

// ---------------------------------------------------------------------------
// gemm1: H = relu(Xf @ W1[e] + b1[e]).  M-tile 64, N=256, K=4096, BK=128.
// Epilogue writes HP in fragment-packed order for gemm2.
// ---------------------------------------------------------------------------
template <int USEXBF>
__global__ __launch_bounds__(512) void gemm1_kernel(
    const float* __restrict__ X, const bf16* __restrict__ Xbf,
    const bf16* __restrict__ W1P, const float* __restrict__ b1,
    bf16* __restrict__ HP) {
  __shared__ __align__(16) bf16 Ab[2][64 * 136];
  const int fid = blockIdx.x;
  const int e = (fid & 7) >> 1;
  const int m = ((fid >> 3) << 1) | (fid & 1);    // 0..63
  const int b0 = m * 64;
  const int tid = threadIdx.x, lane = tid & 63, w = tid >> 6;
  const int wm = w >> 2, wn = w & 3;
  const int lr = lane & 15, g = lane >> 4;

  const int arow = tid >> 3, ak0 = (tid & 7) * 16;
  const size_t abase = (size_t)(b0 + arow) * 16384 + e * 4096 + ak0;
  const bf16* Wp = W1P + (size_t)e * 128 * 16 * 512;

  f32x4 acc[2][4];
#pragma unroll
  for (int i = 0; i < 2; i++)
#pragma unroll
    for (int j = 0; j < 4; j++) acc[i][j] = zero4();

  f32x4 p0, p1, p2, p3;
  bf16x8 q0, q1;
  if (USEXBF) {
    q0 = *(const bf16x8*)&Xbf[abase];
    q1 = *(const bf16x8*)&Xbf[abase + 8];
  } else {
    const float* q = X + abase;
    p0 = *(const f32x4*)q;       p1 = *(const f32x4*)(q + 4);
    p2 = *(const f32x4*)(q + 8); p3 = *(const f32x4*)(q + 12);
  }

  for (int kt = 0; kt < 32; kt++) {
    const int cur = kt & 1;
    if (USEXBF) {
      *(bf16x8*)&Ab[cur][arow * 136 + ak0] = q0;
      *(bf16x8*)&Ab[cur][arow * 136 + ak0 + 8] = q1;
      if (kt < 31) {
        q0 = *(const bf16x8*)&Xbf[abase + (kt + 1) * 128];
        q1 = *(const bf16x8*)&Xbf[abase + (kt + 1) * 128 + 8];
      }
    } else {
      *(bf16x8*)&Ab[cur][arow * 136 + ak0] = cvt8(p0, p1);
      *(bf16x8*)&Ab[cur][arow * 136 + ak0 + 8] = cvt8(p2, p3);
      if (kt < 31) {
        const float* q = X + abase + (kt + 1) * 128;
        p0 = *(const f32x4*)q;       p1 = *(const f32x4*)(q + 4);
        p2 = *(const f32x4*)(q + 8); p3 = *(const f32x4*)(q + 12);
      }
    }
    __syncthreads();
#pragma unroll
    for (int kki = 0; kki < 4; kki++) {
      const int kc = kt * 4 + kki;
      bf16x8 afr[2], bfr[4];
#pragma unroll
      for (int i = 0; i < 2; i++)
        afr[i] = *(const bf16x8*)&Ab[cur][(wm * 32 + i * 16 + lr) * 136 +
                                          kki * 32 + g * 8];
#pragma unroll
      for (int j = 0; j < 4; j++)
        bfr[j] = *(const bf16x8*)&Wp[(((size_t)kc) * 16 + wn * 4 + j) * 512 +
                                     lane * 8];
#pragma unroll
      for (int i = 0; i < 2; i++)
#pragma unroll
        for (int j = 0; j < 4; j++)
          acc[i][j] = __builtin_amdgcn_mfma_f32_16x16x32_bf16(afr[i], bfr[j],
                                                              acc[i][j], 0, 0, 0);
    }
    __syncthreads();
  }
  // epilogue: relu(acc + b1) -> HP (fragment-packed)
#pragma unroll
  for (int j = 0; j < 4; j++) {
    const int col = wn * 64 + j * 16 + lr;
    const float bv = b1[e * 256 + col];
    const int kc = col >> 5, lhi = (col >> 3) & 3, jj = col & 7;
#pragma unroll
    for (int i = 0; i < 2; i++) {
      const int mfg = m * 4 + wm * 2 + i;
      bf16* dst = HP + (((size_t)e * 256 + mfg) * 8 + kc) * 512 + jj;
#pragma unroll
      for (int r = 0; r < 4; r++) {
        float v = fmaxf(acc[i][j][r] + bv, 0.f);
        dst[(lhi * 16 + g * 4 + r) * 8] = (bf16)v;
      }
    }
  }
}

// ---------------------------------------------------------------------------
// gemm2 r8: swapped operands. Block 256 thr = 4 waves; wave = one 16-row
// group x all 256 d of one (e,t). mfma(A=W2frag, B=Hfrag): lane lr = batch
// row, (g,r) = d. No LDS, no barriers. W2 streamed with 3-slot register
// ring; H (8 frags) resident. Epilogue: residual + 2-shuffle LN + f32x4.
// ---------------------------------------------------------------------------
#define G2_LOAD(S, NF)                                               \
  {                                                                  \
    _Pragma("unroll") for (int kc = 0; kc < 8; kc++)                 \
        S[kc] = *(const bf16x8*)&Wp[(size_t)((NF)*8 + kc) * 512];    \
  }
#define G2_MFMA(S, NF)                                               \
  {                                                                  \
    _Pragma("unroll") for (int kc = 0; kc < 8; kc++)                 \
        acc[NF] = __builtin_amdgcn_mfma_f32_16x16x32_bf16(           \
            S[kc], hreg[kc], acc[NF], 0, 0, 0);                      \
  }

__global__ __launch_bounds__(256, 2) void gemm2_kernel(
    const bf16* __restrict__ HP, const bf16* __restrict__ W2P,
    const float* __restrict__ b2, const float* __restrict__ gamma,
    const float* __restrict__ beta, const float* __restrict__ Y0f,
    const bf16* __restrict__ Y0b, int useBf, float* __restrict__ Out) {
  const int tid = threadIdx.x, lane = tid & 63, w = tid >> 6;
  const int lr = lane & 15, g = lane >> 4;
  const int fid = blockIdx.x;
  const int e = fid & 3;          // (e,t) pinned per XCD via fid&7
  const int rest = fid >> 2;      // 0..1023
  const int t = rest & 15;
  const int ms = rest >> 4;       // 0..63
  const int mg = ms * 4 + w;      // 16-row group, 0..255
  const int b0 = mg * 16;

  const bf16* Hp = HP + (((size_t)e * 256 + mg) * 8) * 512 + lane * 8;
  const bf16* Wp = W2P + (((size_t)e * 256 + t * 16) * 8) * 512 + lane * 8;

  // resident B: H frags for this row-group
  bf16x8 hreg[8];
#pragma unroll
  for (int kc = 0; kc < 8; kc++)
    hreg[kc] = *(const bf16x8*)&Hp[(size_t)kc * 512];

  f32x4 acc[16];
#pragma unroll
  for (int nf = 0; nf < 16; nf++) acc[nf] = zero4();

  bf16x8 sA[8], sB[8], sC[8];
  G2_LOAD(sA, 0) G2_LOAD(sB, 1) G2_LOAD(sC, 2)
  G2_MFMA(sA, 0)  G2_LOAD(sA, 3)
  G2_MFMA(sB, 1)  G2_LOAD(sB, 4)
  G2_MFMA(sC, 2)  G2_LOAD(sC, 5)
  G2_MFMA(sA, 3)  G2_LOAD(sA, 6)
  G2_MFMA(sB, 4)  G2_LOAD(sB, 7)
  G2_MFMA(sC, 5)  G2_LOAD(sC, 8)
  G2_MFMA(sA, 6)  G2_LOAD(sA, 9)
  G2_MFMA(sB, 7)  G2_LOAD(sB, 10)
  G2_MFMA(sC, 8)  G2_LOAD(sC, 11)
  G2_MFMA(sA, 9)  G2_LOAD(sA, 12)
  G2_MFMA(sB, 10) G2_LOAD(sB, 13)
  G2_MFMA(sC, 11) G2_LOAD(sC, 14)
  G2_MFMA(sA, 12) G2_LOAD(sA, 15)
  G2_MFMA(sB, 13)
  G2_MFMA(sC, 14)
  G2_MFMA(sA, 15)

  // epilogue: lane owns row b0+lr, d = nf*16 + g*4 + r
  const size_t rowb = (size_t)(b0 + lr) * 16384 + e * 4096 + t * 256 + g * 4;
  const int dbase = t * 256 + g * 4;

  float s1 = 0.f, s2 = 0.f;
#pragma unroll
  for (int nf = 0; nf < 16; nf++) {
    f32x4 bv = *(const f32x4*)&b2[e * 4096 + dbase + nf * 16];
    f32x4 y0;
    if (useBf) {
      bf16x4 yv = *(const bf16x4*)&Y0b[rowb + nf * 16];
      y0.x = (float)yv[0]; y0.y = (float)yv[1];
      y0.z = (float)yv[2]; y0.w = (float)yv[3];
    } else {
      y0 = *(const f32x4*)&Y0f[rowb + nf * 16];
    }
#pragma unroll
    for (int r = 0; r < 4; r++) {
      float v = acc[nf][r] + bv[r] + y0[r];
      acc[nf][r] = v;
      s1 += v;
      s2 += v * v;
    }
  }
  s1 += __shfl_xor(s1, 16); s1 += __shfl_xor(s1, 32);
  s2 += __shfl_xor(s2, 16); s2 += __shfl_xor(s2, 32);
  const float mu = s1 * (1.f / 256.f);
  const float var = s2 * (1.f / 256.f) - mu * mu;
  const float rs = rsqrtf(var + 1e-5f);

#pragma unroll
  for (int nf = 0; nf < 16; nf++) {
    f32x4 gv = *(const f32x4*)&gamma[e * 256 + (g * 4) + nf * 16];
    f32x4 bt = *(const f32x4*)&beta[e * 256 + (g * 4) + nf * 16];
    f32x4 o;
#pragma unroll
    for (int r = 0; r < 4; r++)
      o[r] = (acc[nf][r] - mu) * rs * gv[r] + bt[r];
    *(f32x4*)&Out[rowb + nf * 16] = o;
  }
}

// ---------------------------------------------------------------------------
extern "C" void kernel_launch(void* const* d_in, const int* in_sizes, int n_in,
                              void* d_out, int out_size, void* d_ws, size_t ws_size,
                              hipStream_t stream) {
  const float* X     = (const float*)d_in[0];
  const float* W1    = (const float*)d_in[1];
  const float* b1    = (const float*)d_in[2];
  const float* W2    = (const float*)d_in[3];
  const float* b2    = (const float*)d_in[4];
  const float* gamma = (const float*)d_in[5];
  const float* beta  = (const float*)d_in[6];
  float* Out = (float*)d_out;

  const size_t MB8 = (size_t)4 * 1048576;        // 4M bf16 elems = 8 MB
  bf16* W1P = (bf16*)d_ws;                       // 8 MB
  bf16* W2P = W1P + MB8;                         // 8 MB
  bf16* HP  = W2P + MB8;                         // 8 MB (fragment-packed H)
  bf16* Y0b = HP + MB8;                          // 134 MB
  bf16* Xbf = Y0b + (size_t)4096 * 16384;        // 134 MB

  const size_t bigN = (size_t)4096 * 16384 * 2;  // 134,217,728 B
  const size_t base = 3 * (MB8 * 2);             // 25,165,824 B
  const int useBf = (ws_size >= base + bigN) ? 1 : 0;
  const int useXb = (ws_size >= base + 2 * bigN) ? 1 : 0;

  pack_w1<<<dim3(4, 128, 4), dim3(256), 0, stream>>>(W1, W1P);
  pack_w2<<<dim3(8, 16, 4), dim3(256), 0, stream>>>(W2, W2P);
  attn_kernel<<<dim3(4096), dim3(256), 0, stream>>>(X, Out, Y0b, Xbf, useBf, useXb);
  if (useXb)
    gemm1_kernel<1><<<dim3(256), dim3(512), 0, stream>>>(X, Xbf, W1P, b1, HP);
  else
    gemm1_kernel<0><<<dim3(256), dim3(512), 0, stream>>>(X, Xbf, W1P, b1, HP);
  gemm2_kernel<<<dim3(4096), dim3(256), 0, stream>>>(HP, W2P, b2, gamma, beta,
                                                     Out, Y0b, useBf, Out);
}

// Round 9
// 417.793 us; speedup vs baseline: 1.3089x; 1.1783x over previous
//
#include <hip/hip_runtime.h>

// GlobalInteraction r9: B=4096, N_GLOBAL=64, D=256, E=4, TPE=16, F=4096
// X:(B,64,256) f32; W1:(E,4096,256); b1:(E,256); W2:(E,256,4096); b2:(E,4096);
// gamma,beta:(E,256). Out:(B,64,256) f32.
//
// fused_ag: block=(e, 32 b's). Phase 1 = per-wave attention (4 waves x 8
// pairs) -> Y0b (bf16). Phase 2 = gemm1 M=32 (X f32, L2/L3-warm from phase 1)
// -> HP fragment-packed. No Xbf round-trip.
// gemm2: r6 structure (W2 B-frags register-resident per block), grid 2048
// (2 m-tiles/block) for occupancy.

typedef __attribute__((ext_vector_type(4))) float f32x4;
typedef __bf16 bf16;
typedef __attribute__((ext_vector_type(8))) bf16 bf16x8;

#define DEV static __device__ __forceinline__

DEV f32x4 zero4() { return f32x4{0.f, 0.f, 0.f, 0.f}; }

DEV bf16x8 cvt8(const f32x4& a, const f32x4& b) {
  bf16x8 o;
  o[0] = (bf16)a.x; o[1] = (bf16)a.y; o[2] = (bf16)a.z; o[3] = (bf16)a.w;
  o[4] = (bf16)b.x; o[5] = (bf16)b.y; o[6] = (bf16)b.z; o[7] = (bf16)b.w;
  return o;
}

// ---------------------------------------------------------------------------
// pack_w1: W1 (E,4096,256) f32 -> fragment-packed bf16.
// Frag (kc,nf): lane l, elem j = W1[e][kc*32+(l>>4)*8+j][nf*16+(l&15)]
// ---------------------------------------------------------------------------
__global__ __launch_bounds__(256) void pack_w1(const float* __restrict__ W1,
                                               bf16* __restrict__ P) {
  const int e = blockIdx.z, kc = blockIdx.y;
  const int nf = blockIdx.x * 4 + (threadIdx.x >> 6);
  const int l = threadIdx.x & 63;
  const float* src = W1 + (size_t)e * 4096 * 256 +
                     (size_t)(kc * 32 + (l >> 4) * 8) * 256 + nf * 16 + (l & 15);
  bf16x8 o;
#pragma unroll
  for (int j = 0; j < 8; j++) o[j] = (bf16)src[(size_t)j * 256];
  *(bf16x8*)&P[(((size_t)e * 128 + kc) * 16 + nf) * 512 + l * 8] = o;
}

// ---------------------------------------------------------------------------
// pack_w2: W2 (E,256,4096) f32 -> fragment-packed bf16.
// Frag (t,nfl,kc): lane l, j = W2[e][kc*32+(l>>4)*8+j][t*256+nfl*16+(l&15)]
// ---------------------------------------------------------------------------
__global__ __launch_bounds__(256) void pack_w2(const float* __restrict__ W2,
                                               bf16* __restrict__ P) {
  const int e = blockIdx.z, t = blockIdx.y, kc = blockIdx.x;
  const int l = threadIdx.x & 63;
#pragma unroll
  for (int it = 0; it < 4; it++) {
    int nfl = it * 4 + (threadIdx.x >> 6);
    const float* src = W2 + (size_t)e * 256 * 4096 +
                       (size_t)(kc * 32 + (l >> 4) * 8) * 4096 + t * 256 +
                       nfl * 16 + (l & 15);
    bf16x8 o;
#pragma unroll
    for (int j = 0; j < 8; j++) o[j] = (bf16)src[(size_t)j * 4096];
    *(bf16x8*)&P[(((size_t)e * 256 + t * 16 + nfl) * 8 + kc) * 512 + l * 8] = o;
  }
}

// ---------------------------------------------------------------------------
// fused_ag: phase 1 attention (4 waves x 8 pairs) -> Y0b;
//           phase 2 gemm1 M=32 -> HP (fragment-packed). 256 threads.
// ---------------------------------------------------------------------------
__global__ __launch_bounds__(256) void fused_ag(
    const float* __restrict__ X, const bf16* __restrict__ W1P,
    const float* __restrict__ b1, float* __restrict__ Y0f,
    bf16* __restrict__ Y0b, bf16* __restrict__ HP, int useBf) {
  // S: phase1 = 4 per-wave XpT buffers [4224]; phase2 = Ab dbuf 2x[32*136]
  __shared__ __align__(16) bf16 S[4 * 4224];   // 33,792 B
  __shared__ __align__(16) bf16 Pl[4 * 512];   //  4,096 B
  const int tid = threadIdx.x, lane = tid & 63, w = tid >> 6;
  const int lr = lane & 15, g = lane >> 4;
  const int fid = blockIdx.x;                  // 512 blocks
  const int e = (fid & 7) >> 1;                // expert per XCD-pair
  const int m = ((fid >> 3) << 1) | (fid & 1); // 0..127
  const int b0 = m * 32;

  // ---------------- phase 1: attention ----------------
  {
    bf16* xt = &S[w * 4224];
    bf16* pl = &Pl[w * 512];
    // zero P pad cols 16..31 (persists across pairs: softmax writes cols<16)
    for (int q = lane; q < 256; q += 64) {
      int row = q >> 4, cc = q & 15;
      pl[row * 32 + 16 + cc] = (bf16)0.f;
    }

    for (int q = 0; q < 8; q++) {
      const int bp = b0 + q * 4 + w;
      const size_t obase0 = (size_t)bp * 16384 + e * 4096;
      const float* Xb = X + obase0;

      xt[4096 + lane] = (bf16)0.f;  // re-zero tail pad (clobbered by Yl)

      bf16x8 af[8];
#pragma unroll
      for (int c = 0; c < 8; c++) {
        const float* qq = Xb + lr * 256 + c * 32 + g * 8;
        f32x4 v0 = *(const f32x4*)qq;
        f32x4 v1 = *(const f32x4*)(qq + 4);
        bf16x8 o = cvt8(v0, v1);
        af[c] = o;
#pragma unroll
        for (int j = 0; j < 8; j++)
          xt[(c * 32 + g * 8 + j) * 16 + lr] = o[j];
      }

      f32x4 s = zero4();
#pragma unroll
      for (int c = 0; c < 8; c++)
        s = __builtin_amdgcn_mfma_f32_16x16x32_bf16(af[c], af[c], s, 0, 0, 0);

      float pv[4];
#pragma unroll
      for (int r = 0; r < 4; r++) {
        float v = s[r] * 0.0625f;
        float mx = v;
#pragma unroll
        for (int mm = 1; mm < 16; mm <<= 1) mx = fmaxf(mx, __shfl_xor(mx, mm));
        float ev = __expf(v - mx);
        float sum = ev;
#pragma unroll
        for (int mm = 1; mm < 16; mm <<= 1) sum += __shfl_xor(sum, mm);
        pv[r] = ev / sum;
      }
#pragma unroll
      for (int r = 0; r < 4; r++) pl[(g * 4 + r) * 32 + lr] = (bf16)pv[r];
      bf16x8 pf = *(const bf16x8*)&pl[lr * 32 + g * 8];

      float yo[16][4];
#pragma unroll
      for (int nc = 0; nc < 16; nc++) {
        bf16x8 bfr = *(const bf16x8*)&xt[(nc * 16 + lr) * 16 + g * 8];
        f32x4 xd =
            __builtin_amdgcn_mfma_f32_16x16x32_bf16(pf, bfr, zero4(), 0, 0, 0);
#pragma unroll
        for (int r = 0; r < 4; r++)
          yo[nc][r] = xd[r] + (float)xt[(nc * 16 + lr) * 16 + g * 4 + r];
      }

      // transpose via LDS overlay Yl[16][264] (same-wave LDS is in-order)
#pragma unroll
      for (int nc = 0; nc < 16; nc++)
#pragma unroll
        for (int r = 0; r < 4; r++)
          xt[(g * 4 + r) * 264 + nc * 16 + lr] = (bf16)yo[nc][r];

      const int tok = lane >> 2, cc = lane & 3;
      if (useBf) {
#pragma unroll
        for (int i = 0; i < 8; i++) {
          int d0 = i * 32 + cc * 8;
          bf16x8 v = *(const bf16x8*)&xt[tok * 264 + d0];
          *(bf16x8*)&Y0b[obase0 + tok * 256 + d0] = v;
        }
      } else {
#pragma unroll
        for (int i = 0; i < 8; i++) {
          int d0 = i * 32 + cc * 8;
          bf16x8 v = *(const bf16x8*)&xt[tok * 264 + d0];
          f32x4 a, bb;
          a.x = (float)v[0]; a.y = (float)v[1];
          a.z = (float)v[2]; a.w = (float)v[3];
          bb.x = (float)v[4]; bb.y = (float)v[5];
          bb.z = (float)v[6]; bb.w = (float)v[7];
          *(f32x4*)&Y0f[obase0 + tok * 256 + d0] = a;
          *(f32x4*)&Y0f[obase0 + tok * 256 + d0 + 4] = bb;
        }
      }
    }
  }
  __syncthreads();  // phase 1 done; reuse S as Ab

  // ---------------- phase 2: gemm1 (M=32, X f32, L2/L3-warm) ----------------
  {
    bf16* Ab0 = S;           // [32*136]
    bf16* Ab1 = S + 4352;    // [32*136]
    const int arow = tid >> 3, ak0 = (tid & 7) * 16;
    const size_t abase = (size_t)(b0 + arow) * 16384 + e * 4096 + ak0;
    const bf16* Wp = W1P + (size_t)e * 128 * 16 * 512;

    f32x4 acc[2][4];
#pragma unroll
    for (int i = 0; i < 2; i++)
#pragma unroll
      for (int j = 0; j < 4; j++) acc[i][j] = zero4();

    f32x4 p0, p1, p2, p3;
    {
      const float* q = X + abase;
      p0 = *(const f32x4*)q;       p1 = *(const f32x4*)(q + 4);
      p2 = *(const f32x4*)(q + 8); p3 = *(const f32x4*)(q + 12);
    }

    for (int kt = 0; kt < 32; kt++) {
      bf16* Ac = (kt & 1) ? Ab1 : Ab0;
      *(bf16x8*)&Ac[arow * 136 + ak0] = cvt8(p0, p1);
      *(bf16x8*)&Ac[arow * 136 + ak0 + 8] = cvt8(p2, p3);
      if (kt < 31) {
        const float* q = X + abase + (kt + 1) * 128;
        p0 = *(const f32x4*)q;       p1 = *(const f32x4*)(q + 4);
        p2 = *(const f32x4*)(q + 8); p3 = *(const f32x4*)(q + 12);
      }
      __syncthreads();
#pragma unroll
      for (int kki = 0; kki < 4; kki++) {
        const int kc = kt * 4 + kki;
        bf16x8 afr[2], bfr[4];
#pragma unroll
        for (int i = 0; i < 2; i++)
          afr[i] = *(const bf16x8*)&Ac[(i * 16 + lr) * 136 + kki * 32 + g * 8];
#pragma unroll
        for (int j = 0; j < 4; j++)
          bfr[j] = *(const bf16x8*)&Wp[(((size_t)kc) * 16 + w * 4 + j) * 512 +
                                       lane * 8];
#pragma unroll
        for (int i = 0; i < 2; i++)
#pragma unroll
          for (int j = 0; j < 4; j++)
            acc[i][j] = __builtin_amdgcn_mfma_f32_16x16x32_bf16(
                afr[i], bfr[j], acc[i][j], 0, 0, 0);
      }
      __syncthreads();
    }
    // epilogue: relu(acc + b1) -> HP (fragment-packed)
#pragma unroll
    for (int j = 0; j < 4; j++) {
      const int col = w * 64 + j * 16 + lr;
      const float bv = b1[e * 256 + col];
      const int kc = col >> 5, lhi = (col >> 3) & 3, jj = col & 7;
#pragma unroll
      for (int i = 0; i < 2; i++) {
        const int mfg = m * 2 + i;
        bf16* dst = HP + (((size_t)e * 256 + mfg) * 8 + kc) * 512 + jj;
#pragma unroll
        for (int r = 0; r < 4; r++) {
          float v = fmaxf(acc[i][j][r] + bv, 0.f);
          dst[(lhi * 16 + g * 4 + r) * 8] = (bf16)v;
        }
      }
    }
  }
}

// ---------------------------------------------------------------------------
// gemm2 (r6 structure, finer grid): block=(e,t,ms); 2 m-tiles per block.
// 512 thr = 8 waves x 32 n-cols. W2 B-frags register-resident; A from packed
// HP; T-transpose epilogue + fused LN.
// ---------------------------------------------------------------------------
__global__ __launch_bounds__(512) void gemm2_kernel(
    const bf16* __restrict__ HP, const bf16* __restrict__ W2P,
    const float* __restrict__ b2, const float* __restrict__ gamma,
    const float* __restrict__ beta, const float* __restrict__ Y0f,
    const bf16* __restrict__ Y0b, int useBf, float* __restrict__ Out) {
  __shared__ __align__(16) bf16 T[64 * 264];
  const int fid = blockIdx.x;      // 2048 blocks
  const int e = fid & 3;           // e pinned per XCD (fid&7 RR)
  const int rr_ = fid >> 2;        // 0..511
  const int t = rr_ & 15;
  const int ms = rr_ >> 4;         // 0..31
  const int tid = threadIdx.x, lane = tid & 63, w = tid >> 6;  // w 0..7
  const int lr = lane & 15, g = lane >> 4;
  const int erow = tid >> 3, ec = tid & 7;

  // resident B: wave w owns cols [w*32, w*32+32)
  bf16x8 breg[2][8];
  {
    const bf16* Wp = W2P + (((size_t)e * 256 + t * 16 + w * 2) * 8) * 512 +
                     lane * 8;
#pragma unroll
    for (int nj = 0; nj < 2; nj++)
#pragma unroll
      for (int kc = 0; kc < 8; kc++)
        breg[nj][kc] = *(const bf16x8*)&Wp[(size_t)(nj * 8 + kc) * 512];
  }
  float b2v[2];
#pragma unroll
  for (int nj = 0; nj < 2; nj++)
    b2v[nj] = b2[e * 4096 + t * 256 + w * 32 + nj * 16 + lr];

  for (int it = 0; it < 2; it++) {
    const int mt = ms * 2 + it;
    const int b0 = mt * 64;
    const size_t ebase =
        (size_t)(b0 + erow) * 16384 + e * 4096 + t * 256 + ec * 32;

    // Y0 prefetch (overlaps MFMA phase)
    bf16x8 y0r[4];
    if (useBf) {
#pragma unroll
      for (int u = 0; u < 4; u++)
        y0r[u] = *(const bf16x8*)&Y0b[ebase + u * 8];
    }

    // MFMA: A from HP (coalesced packed), 1-deep kc pipeline
    const bf16* Ap = HP + (((size_t)e * 256 + mt * 4) * 8) * 512 + lane * 8;
    f32x4 acc[4][2];
#pragma unroll
    for (int mf = 0; mf < 4; mf++)
#pragma unroll
      for (int nj = 0; nj < 2; nj++) acc[mf][nj] = zero4();

    bf16x8 afr[4], afn[4];
#pragma unroll
    for (int mf = 0; mf < 4; mf++)
      afr[mf] = *(const bf16x8*)&Ap[(size_t)(mf * 8) * 512];
#pragma unroll
    for (int kc = 0; kc < 8; kc++) {
      if (kc < 7) {
#pragma unroll
        for (int mf = 0; mf < 4; mf++)
          afn[mf] = *(const bf16x8*)&Ap[(size_t)(mf * 8 + kc + 1) * 512];
      }
#pragma unroll
      for (int mf = 0; mf < 4; mf++)
#pragma unroll
        for (int nj = 0; nj < 2; nj++)
          acc[mf][nj] = __builtin_amdgcn_mfma_f32_16x16x32_bf16(
              afr[mf], breg[nj][kc], acc[mf][nj], 0, 0, 0);
#pragma unroll
      for (int mf = 0; mf < 4; mf++) afr[mf] = afn[mf];
    }

    __syncthreads();  // prior epilogue's T reads complete
#pragma unroll
    for (int mf = 0; mf < 4; mf++)
#pragma unroll
      for (int nj = 0; nj < 2; nj++)
#pragma unroll
        for (int r = 0; r < 4; r++)
          T[(mf * 16 + g * 4 + r) * 264 + w * 32 + nj * 16 + lr] =
              (bf16)(acc[mf][nj][r] + b2v[nj]);
    __syncthreads();

    // epilogue: thread owns row erow, cols [ec*32, ec*32+32)
    float y[4][8];
    float s1 = 0.f, s2 = 0.f;
#pragma unroll
    for (int u = 0; u < 4; u++) {
      bf16x8 tv = *(const bf16x8*)&T[erow * 264 + ec * 32 + u * 8];
      if (useBf) {
#pragma unroll
        for (int u8 = 0; u8 < 8; u8++) {
          float v = (float)tv[u8] + (float)y0r[u][u8];
          y[u][u8] = v;
          s1 += v;
          s2 += v * v;
        }
      } else {
        f32x4 a = *(const f32x4*)&Y0f[ebase + u * 8];
        f32x4 bb = *(const f32x4*)&Y0f[ebase + u * 8 + 4];
#pragma unroll
        for (int u8 = 0; u8 < 8; u8++) {
          float v = (float)tv[u8] + (u8 < 4 ? a[u8] : bb[u8 - 4]);
          y[u][u8] = v;
          s1 += v;
          s2 += v * v;
        }
      }
    }
    s1 += __shfl_xor(s1, 1); s1 += __shfl_xor(s1, 2); s1 += __shfl_xor(s1, 4);
    s2 += __shfl_xor(s2, 1); s2 += __shfl_xor(s2, 2); s2 += __shfl_xor(s2, 4);
    const float mu = s1 * (1.f / 256.f);
    const float var = s2 * (1.f / 256.f) - mu * mu;
    const float rs = rsqrtf(var + 1e-5f);

#pragma unroll
    for (int u = 0; u < 4; u++) {
      const int col = ec * 32 + u * 8;
      f32x4 gv0 = *(const f32x4*)&gamma[e * 256 + col];
      f32x4 gv1 = *(const f32x4*)&gamma[e * 256 + col + 4];
      f32x4 bt0 = *(const f32x4*)&beta[e * 256 + col];
      f32x4 bt1 = *(const f32x4*)&beta[e * 256 + col + 4];
      f32x4 o0, o1;
#pragma unroll
      for (int u8 = 0; u8 < 4; u8++) {
        o0[u8] = (y[u][u8] - mu) * rs * gv0[u8] + bt0[u8];
        o1[u8] = (y[u][u8 + 4] - mu) * rs * gv1[u8] + bt1[u8];
      }
      *(f32x4*)&Out[ebase + u * 8] = o0;
      *(f32x4*)&Out[ebase + u * 8 + 4] = o1;
    }
  }
}

// ---------------------------------------------------------------------------
extern "C" void kernel_launch(void* const* d_in, const int* in_sizes, int n_in,
                              void* d_out, int out_size, void* d_ws, size_t ws_size,
                              hipStream_t stream) {
  const float* X     = (const float*)d_in[0];
  const float* W1    = (const float*)d_in[1];
  const float* b1    = (const float*)d_in[2];
  const float* W2    = (const float*)d_in[3];
  const float* b2    = (const float*)d_in[4];
  const float* gamma = (const float*)d_in[5];
  const float* beta  = (const float*)d_in[6];
  float* Out = (float*)d_out;

  const size_t MB8 = (size_t)4 * 1048576;        // 4M bf16 elems = 8 MB
  bf16* W1P = (bf16*)d_ws;                       // 8 MB
  bf16* W2P = W1P + MB8;                         // 8 MB
  bf16* HP  = W2P + MB8;                         // 8 MB (fragment-packed H)
  bf16* Y0b = HP + MB8;                          // 134 MB

  const size_t bigN = (size_t)4096 * 16384 * 2;  // 134,217,728 B
  const size_t base = 3 * (MB8 * 2);             // 25,165,824 B
  const int useBf = (ws_size >= base + bigN) ? 1 : 0;

  pack_w1<<<dim3(4, 128, 4), dim3(256), 0, stream>>>(W1, W1P);
  pack_w2<<<dim3(8, 16, 4), dim3(256), 0, stream>>>(W2, W2P);
  fused_ag<<<dim3(512), dim3(256), 0, stream>>>(X, W1P, b1, Out, Y0b, HP, useBf);
  gemm2_kernel<<<dim3(2048), dim3(512), 0, stream>>>(HP, W2P, b2, gamma, beta,
                                                     Out, Y0b, useBf, Out);
}